// Round 10
// baseline (48.272 us; speedup 1.0000x reference)
//
#include <hip/hip_runtime.h>
#include <math.h>

#define N_NODES 100000
#define N_EDGES 1600000
#define IN_DIM  128
#define OUT_DIM 32
#define LEAKY   0.2f

#define GEMM_NBLK 782         // ceil(N_NODES/128)
#define OFF_NBLK  6250        // ceil(N_EDGES/256)

typedef unsigned int uint;
typedef unsigned short ushort;
typedef __attribute__((ext_vector_type(8))) short bf16x8;
typedef __attribute__((ext_vector_type(4))) float f32x4;

// round-to-nearest-even fp32 -> bf16 (as ushort bit pattern)
__device__ __forceinline__ ushort rne16(float f) {
    uint u = __float_as_uint(f);
    return (ushort)((u + 0x7fffu + ((u >> 16) & 1u)) >> 16);
}

// ------- Kernel A+B fused: MFMA gemm (blocks < GEMM_NBLK) | CSR offsets -----
// gemm: each wave now owns TWO 16-row A-fragments (32 rows; block = 128 rows).
// 16 X float4 loads issued up front (2x MLP), 16 MFMAs in 4 independent
// chains, W-staging + B-frag ds_reads amortized over 2x rows. Round 9 showed
// instruction count is NOT the bound -> this attacks exposed load latency.
__global__ __launch_bounds__(256) void gemm_off_kernel(
    const float* __restrict__ X, const float* __restrict__ W,
    const float* __restrict__ a_src, const float* __restrict__ a_dst,
    const int* __restrict__ dst,
    ushort* __restrict__ zu16, float* __restrict__ ssrc, float* __restrict__ sdst,
    int* __restrict__ off)
{
    __shared__ ushort WT[32][136];     // WT[c][k], bf16 bits; 272B rows
    __shared__ float asl[OUT_DIM], adl[OUT_DIM];

    if (blockIdx.x >= GEMM_NBLK) {
        // ---------------- offsets body ----------------
        const int e = (blockIdx.x - GEMM_NBLK) * 256 + threadIdx.x;
        if (e >= N_EDGES) return;
        const int d = dst[e];
        const int dprev = (e == 0) ? -1 : dst[e - 1];
        for (int n = dprev + 1; n <= d; ++n) off[n] = e;
        if (e == N_EDGES - 1) {
            for (int n = d + 1; n <= N_NODES; ++n) off[n] = N_EDGES;
        }
        return;
    }

    // ---------------- gemm body ----------------
    const int t    = threadIdx.x;
    const int lane = t & 63;
    const int wv   = t >> 6;
    const int m    = lane & 15;
    const int kg   = lane >> 4;

    const int rowBase = blockIdx.x * 128 + wv * 32;
    int r0 = rowBase + m;      if (r0 > N_NODES - 1) r0 = N_NODES - 1;
    int r1 = rowBase + 16 + m; if (r1 > N_NODES - 1) r1 = N_NODES - 1;
    const float* xp0 = X + (size_t)r0 * IN_DIM + (kg << 3);
    const float* xp1 = X + (size_t)r1 * IN_DIM + (kg << 3);

    // 16 independent float4 loads in flight during W staging
    float4 x0A[4], x0B[4], x1A[4], x1B[4];
    #pragma unroll
    for (int s = 0; s < 4; ++s) {
        x0A[s] = *reinterpret_cast<const float4*>(xp0 + (s << 5));
        x0B[s] = *reinterpret_cast<const float4*>(xp0 + (s << 5) + 4);
        x1A[s] = *reinterpret_cast<const float4*>(xp1 + (s << 5));
        x1B[s] = *reinterpret_cast<const float4*>(xp1 + (s << 5) + 4);
    }

    // W^T staging: thread t covers col c = t&31, k-chunk kh = t>>5 (16 k's)
    {
        const int c = t & 31, kh = t >> 5;
        uint pk[8];
        #pragma unroll
        for (int j2 = 0; j2 < 8; ++j2) {
            const float w0 = W[(kh * 16 + 2 * j2)     * OUT_DIM + c];
            const float w1 = W[(kh * 16 + 2 * j2 + 1) * OUT_DIM + c];
            pk[j2] = (uint)rne16(w0) | ((uint)rne16(w1) << 16);
        }
        uint4* wd = reinterpret_cast<uint4*>(&WT[c][kh * 16]);
        wd[0] = make_uint4(pk[0], pk[1], pk[2], pk[3]);
        wd[1] = make_uint4(pk[4], pk[5], pk[6], pk[7]);
        if (t < OUT_DIM) { asl[t] = a_src[t]; adl[t] = a_dst[t]; }
    }
    __syncthreads();

    // B fragments: one ds_read_b128 each, shared by both row-fragments
    bf16x8 b0[4], b1[4];
    #pragma unroll
    for (int s = 0; s < 4; ++s) {
        b0[s] = *reinterpret_cast<bf16x8*>(&WT[m][(s << 5) + (kg << 3)]);
        b1[s] = *reinterpret_cast<bf16x8*>(&WT[m + 16][(s << 5) + (kg << 3)]);
    }

    f32x4 acc00 = {0.f,0.f,0.f,0.f}, acc01 = {0.f,0.f,0.f,0.f};
    f32x4 acc10 = {0.f,0.f,0.f,0.f}, acc11 = {0.f,0.f,0.f,0.f};

    #pragma unroll
    for (int s = 0; s < 4; ++s) {
        float xs0[8] = {x0A[s].x, x0A[s].y, x0A[s].z, x0A[s].w,
                        x0B[s].x, x0B[s].y, x0B[s].z, x0B[s].w};
        float xs1[8] = {x1A[s].x, x1A[s].y, x1A[s].z, x1A[s].w,
                        x1B[s].x, x1B[s].y, x1B[s].z, x1B[s].w};
        bf16x8 ah0, ah1;
        #pragma unroll
        for (int j = 0; j < 8; ++j) {
            ah0[j] = (short)rne16(xs0[j]);
            ah1[j] = (short)rne16(xs1[j]);
        }
        acc00 = __builtin_amdgcn_mfma_f32_16x16x32_bf16(ah0, b0[s], acc00, 0, 0, 0);
        acc01 = __builtin_amdgcn_mfma_f32_16x16x32_bf16(ah0, b1[s], acc01, 0, 0, 0);
        acc10 = __builtin_amdgcn_mfma_f32_16x16x32_bf16(ah1, b0[s], acc10, 0, 0, 0);
        acc11 = __builtin_amdgcn_mfma_f32_16x16x32_bf16(ah1, b1[s], acc11, 0, 0, 0);
    }

    // attention scalars for both fragments; butterfly over the 16 m-lanes
    const float as0 = asl[m], as1 = asl[m + 16];
    const float ad0 = adl[m], ad1 = adl[m + 16];
    float ps0[4], pd0[4], ps1[4], pd1[4];
    #pragma unroll
    for (int r = 0; r < 4; ++r) {
        ps0[r] = acc00[r] * as0 + acc01[r] * as1;
        pd0[r] = acc00[r] * ad0 + acc01[r] * ad1;
        ps1[r] = acc10[r] * as0 + acc11[r] * as1;
        pd1[r] = acc10[r] * ad0 + acc11[r] * ad1;
    }
    #pragma unroll
    for (int r = 0; r < 4; ++r) {
        #pragma unroll
        for (int msk = 1; msk <= 8; msk <<= 1) {
            ps0[r] += __shfl_xor(ps0[r], msk, 64);
            pd0[r] += __shfl_xor(pd0[r], msk, 64);
            ps1[r] += __shfl_xor(ps1[r], msk, 64);
            pd1[r] += __shfl_xor(pd1[r], msk, 64);
        }
    }

    const int rb0 = rowBase + (kg << 2);          // frag0 D rows
    const int rb1 = rowBase + 16 + (kg << 2);     // frag1 D rows
    if (m == 0) {
        #pragma unroll
        for (int r = 0; r < 4; ++r) {
            if (rb0 + r < N_NODES) ssrc[rb0 + r] = ps0[r];
            if (rb1 + r < N_NODES) ssrc[rb1 + r] = ps1[r];
        }
    }
    if (m == 1) {
        #pragma unroll
        for (int r = 0; r < 4; ++r) {
            if (rb0 + r < N_NODES) sdst[rb0 + r] = pd0[r];
            if (rb1 + r < N_NODES) sdst[rb1 + r] = pd1[r];
        }
    }

    // z stores: bf16 ushorts, layout zu16[row*32 + c]
    #pragma unroll
    for (int r = 0; r < 4; ++r) {
        const int row0 = rb0 + r, row1 = rb1 + r;
        if (row0 < N_NODES) {
            zu16[row0 * OUT_DIM + m]      = rne16(acc00[r]);
            zu16[row0 * OUT_DIM + m + 16] = rne16(acc01[r]);
        }
        if (row1 < N_NODES) {
            zu16[row1 * OUT_DIM + m]      = rne16(acc10[r]);
            zu16[row1 * OUT_DIM + m + 16] = rne16(acc11[r]);
        }
    }
}

// ---------------- Kernel C: fused exp + gather + normalize ----------------
// TWO nodes per 32-lane group: stage both nodes' chunks (both src loads +
// ssrc gathers in flight), then gather both nodes' z rows (up to 8 b128
// gathers in flight). Per-node instruction count unchanged vs round 9 --
// this doubles latency-chain concurrency, which round 9 showed is the bound.
// eh==0 lanes write node A, eh==1 lanes write node B.
__global__ __launch_bounds__(256) void agg_kernel(
    const uint* __restrict__ zu, const float* __restrict__ ssrc,
    const float* __restrict__ sdst, const int* __restrict__ src,
    const int* __restrict__ off, float* __restrict__ out)
{
    __shared__ float2 sw[8][2][64];
    const int t = threadIdx.x;
    const int g = t >> 5, c = t & 31;
    const int n0 = blockIdx.x * 16 + g * 2;
    if (n0 >= N_NODES) return;
    const int n1 = n0 + 1;
    const bool hasB = (n1 < N_NODES);

    const int loA = off[n0], hiA = off[n0 + 1];
    const int loB = hasB ? off[n1] : 0, hiB = hasB ? off[n1 + 1] : 0;
    const float sdA = sdst[n0];
    const float sdB = hasB ? sdst[n1] : 0.f;

    const int eh = c >> 2;     // edge slot 0..7
    const int ci = c & 3;      // uint4 index within z row

    float aA0=0.f,aA1=0.f,aA2=0.f,aA3=0.f,aA4=0.f,aA5=0.f,aA6=0.f,aA7=0.f;
    float aB0=0.f,aB1=0.f,aB2=0.f,aB3=0.f,aB4=0.f,aB5=0.f,aB6=0.f,aB7=0.f;
    float denA = 0.f, denB = 0.f;

    #define ACC8(A, P, U)                                                  \
        A##0 = fmaf(P.x, __uint_as_float(U.x << 16),         A##0);        \
        A##1 = fmaf(P.x, __uint_as_float(U.x & 0xffff0000u), A##1);        \
        A##2 = fmaf(P.x, __uint_as_float(U.y << 16),         A##2);        \
        A##3 = fmaf(P.x, __uint_as_float(U.y & 0xffff0000u), A##3);        \
        A##4 = fmaf(P.x, __uint_as_float(U.z << 16),         A##4);        \
        A##5 = fmaf(P.x, __uint_as_float(U.z & 0xffff0000u), A##5);        \
        A##6 = fmaf(P.x, __uint_as_float(U.w << 16),         A##6);        \
        A##7 = fmaf(P.x, __uint_as_float(U.w & 0xffff0000u), A##7);

    int baseA = loA, baseB = loB;
    while (baseA < hiA || baseB < hiB) {
        const int cntA = min(32, max(0, hiA - baseA));
        const int cntB = min(32, max(0, hiB - baseB));
        // stage node A chunk
        sw[g][0][cntA + c] = make_float2(0.f, __int_as_float(0));
        if (c < cntA) {
            const int e = baseA + c;
            const int s = src[e];
            float x = ssrc[s] + sdA;
            x = (x > 0.f) ? x : LEAKY * x;
            const float v = __expf(x);
            denA += v;
            sw[g][0][c] = make_float2(v, __int_as_float(s << 4));
        }
        // stage node B chunk
        sw[g][1][cntB + c] = make_float2(0.f, __int_as_float(0));
        if (c < cntB) {
            const int e = baseB + c;
            const int s = src[e];
            float x = ssrc[s] + sdB;
            x = (x > 0.f) ? x : LEAKY * x;
            const float v = __expf(x);
            denB += v;
            sw[g][1][c] = make_float2(v, __int_as_float(s << 4));
        }
        // gather node A
        if (cntA > 0) {
            const float2 p0 = sw[g][0][eh];
            const float2 p1 = sw[g][0][8 + eh];
            const uint4 u0 = *reinterpret_cast<const uint4*>(zu + __float_as_int(p0.y) + (ci << 2));
            const uint4 u1 = *reinterpret_cast<const uint4*>(zu + __float_as_int(p1.y) + (ci << 2));
            ACC8(aA, p0, u0) ACC8(aA, p1, u1)
            if (cntA > 16) {
                const float2 p2 = sw[g][0][16 + eh];
                const float2 p3 = sw[g][0][24 + eh];
                const uint4 u2 = *reinterpret_cast<const uint4*>(zu + __float_as_int(p2.y) + (ci << 2));
                const uint4 u3 = *reinterpret_cast<const uint4*>(zu + __float_as_int(p3.y) + (ci << 2));
                ACC8(aA, p2, u2) ACC8(aA, p3, u3)
            }
        }
        // gather node B
        if (cntB > 0) {
            const float2 p0 = sw[g][1][eh];
            const float2 p1 = sw[g][1][8 + eh];
            const uint4 u0 = *reinterpret_cast<const uint4*>(zu + __float_as_int(p0.y) + (ci << 2));
            const uint4 u1 = *reinterpret_cast<const uint4*>(zu + __float_as_int(p1.y) + (ci << 2));
            ACC8(aB, p0, u0) ACC8(aB, p1, u1)
            if (cntB > 16) {
                const float2 p2 = sw[g][1][16 + eh];
                const float2 p3 = sw[g][1][24 + eh];
                const uint4 u2 = *reinterpret_cast<const uint4*>(zu + __float_as_int(p2.y) + (ci << 2));
                const uint4 u3 = *reinterpret_cast<const uint4*>(zu + __float_as_int(p3.y) + (ci << 2));
                ACC8(aB, p2, u2) ACC8(aB, p3, u3)
            }
        }
        baseA += 32;
        baseB += 32;
    }
    #undef ACC8

    // reduce over the 8 edge slots (lanes sharing ci)
    #pragma unroll
    for (int msk = 4; msk <= 16; msk <<= 1) {
        aA0 += __shfl_xor(aA0, msk, 64); aA1 += __shfl_xor(aA1, msk, 64);
        aA2 += __shfl_xor(aA2, msk, 64); aA3 += __shfl_xor(aA3, msk, 64);
        aA4 += __shfl_xor(aA4, msk, 64); aA5 += __shfl_xor(aA5, msk, 64);
        aA6 += __shfl_xor(aA6, msk, 64); aA7 += __shfl_xor(aA7, msk, 64);
        aB0 += __shfl_xor(aB0, msk, 64); aB1 += __shfl_xor(aB1, msk, 64);
        aB2 += __shfl_xor(aB2, msk, 64); aB3 += __shfl_xor(aB3, msk, 64);
        aB4 += __shfl_xor(aB4, msk, 64); aB5 += __shfl_xor(aB5, msk, 64);
        aB6 += __shfl_xor(aB6, msk, 64); aB7 += __shfl_xor(aB7, msk, 64);
    }
    #pragma unroll
    for (int msk = 16; msk >= 1; msk >>= 1) {
        denA += __shfl_xor(denA, msk, 64);
        denB += __shfl_xor(denB, msk, 64);
    }

    if (eh == 0) {
        const float inv = (denA > 0.f) ? (1.f / denA) : 0.f;
        float4 o0, o1;
        o0.x = fmaxf(aA0 * inv, 0.f); o0.y = fmaxf(aA1 * inv, 0.f);
        o0.z = fmaxf(aA2 * inv, 0.f); o0.w = fmaxf(aA3 * inv, 0.f);
        o1.x = fmaxf(aA4 * inv, 0.f); o1.y = fmaxf(aA5 * inv, 0.f);
        o1.z = fmaxf(aA6 * inv, 0.f); o1.w = fmaxf(aA7 * inv, 0.f);
        float* op = &out[n0 * OUT_DIM + (ci << 3)];
        *reinterpret_cast<float4*>(op)     = o0;
        *reinterpret_cast<float4*>(op + 4) = o1;
    } else if (eh == 1 && hasB) {
        const float inv = (denB > 0.f) ? (1.f / denB) : 0.f;
        float4 o0, o1;
        o0.x = fmaxf(aB0 * inv, 0.f); o0.y = fmaxf(aB1 * inv, 0.f);
        o0.z = fmaxf(aB2 * inv, 0.f); o0.w = fmaxf(aB3 * inv, 0.f);
        o1.x = fmaxf(aB4 * inv, 0.f); o1.y = fmaxf(aB5 * inv, 0.f);
        o1.z = fmaxf(aB6 * inv, 0.f); o1.w = fmaxf(aB7 * inv, 0.f);
        float* op = &out[n1 * OUT_DIM + (ci << 3)];
        *reinterpret_cast<float4*>(op)     = o0;
        *reinterpret_cast<float4*>(op + 4) = o1;
    }
}

// ---------------- launch ----------------
extern "C" void kernel_launch(void* const* d_in, const int* in_sizes, int n_in,
                              void* d_out, int out_size, void* d_ws, size_t ws_size,
                              hipStream_t stream) {
    const float* X     = (const float*)d_in[0];
    const float* W     = (const float*)d_in[1];
    const float* a_src = (const float*)d_in[2];
    const float* a_dst = (const float*)d_in[3];
    const int*   src   = (const int*)d_in[4];
    const int*   dst   = (const int*)d_in[5];
    float* out = (float*)d_out;

    char* ws = (char*)d_ws;
    ushort* zu16 = (ushort*)ws; ws += (size_t)N_NODES * OUT_DIM * sizeof(ushort);
    float* ssrc  = (float*)ws;  ws += (size_t)N_NODES * sizeof(float);
    float* sdst  = (float*)ws;  ws += (size_t)N_NODES * sizeof(float);
    int*   off   = (int*)ws;    ws += (size_t)(N_NODES + 1) * sizeof(int);

    gemm_off_kernel<<<GEMM_NBLK + OFF_NBLK, 256, 0, stream>>>(
        X, W, a_src, a_dst, dst, zu16, ssrc, sdst, off);
    agg_kernel<<<(N_NODES + 15) / 16, 256, 0, stream>>>((const uint*)zu16, ssrc, sdst, src, off, out);
}

// Round 11
// 43.090 us; speedup vs baseline: 1.1203x; 1.1203x over previous
//
#include <hip/hip_runtime.h>
#include <math.h>

#define N_NODES 100000
#define N_EDGES 1600000
#define IN_DIM  128
#define OUT_DIM 32
#define LEAKY   0.2f

#define GEMM_NBLK 1563        // ceil(N_NODES/64)
#define OFF_NBLK  6250        // ceil(N_EDGES/256)

typedef unsigned int uint;
typedef unsigned short ushort;
typedef __attribute__((ext_vector_type(8))) short bf16x8;
typedef __attribute__((ext_vector_type(4))) float f32x4;

// round-to-nearest-even fp32 -> bf16 (as ushort bit pattern)
__device__ __forceinline__ ushort rne16(float f) {
    uint u = __float_as_uint(f);
    return (ushort)((u + 0x7fffu + ((u >> 16) & 1u)) >> 16);
}

// ------- Kernel A+B fused: MFMA gemm (blocks < GEMM_NBLK) | CSR offsets -----
// Structure = the measured-best round-7 submission (43.1us). ONLY change:
// X fragment is single RNE-bf16 (8 MFMA instead of 16 hi/lo; z is stored
// bf16 anyway so storage RNE dominates the error budget). Memory pattern
// identical; strictly less VALU/MFMA work per wave.
__global__ __launch_bounds__(256) void gemm_off_kernel(
    const float* __restrict__ X, const float* __restrict__ W,
    const float* __restrict__ a_src, const float* __restrict__ a_dst,
    const int* __restrict__ dst,
    ushort* __restrict__ zu16, float* __restrict__ ssrc, float* __restrict__ sdst,
    int* __restrict__ off)
{
    __shared__ ushort WT[32][136];     // WT[c][k], bf16 bits; 272B rows
    __shared__ float asl[OUT_DIM], adl[OUT_DIM];

    if (blockIdx.x >= GEMM_NBLK) {
        // ---------------- offsets body ----------------
        const int e = (blockIdx.x - GEMM_NBLK) * 256 + threadIdx.x;
        if (e >= N_EDGES) return;
        const int d = dst[e];
        const int dprev = (e == 0) ? -1 : dst[e - 1];
        for (int n = dprev + 1; n <= d; ++n) off[n] = e;
        if (e == N_EDGES - 1) {
            for (int n = d + 1; n <= N_NODES; ++n) off[n] = N_EDGES;
        }
        return;
    }

    // ---------------- gemm body ----------------
    const int t    = threadIdx.x;
    const int lane = t & 63;
    const int wv   = t >> 6;
    const int m    = lane & 15;
    const int kg   = lane >> 4;

    // X loads first: 8 independent float4 per lane, in flight during staging
    const int rowA = blockIdx.x * 64 + wv * 16 + m;
    const int rA   = (rowA < N_NODES) ? rowA : (N_NODES - 1);
    const float* xp = X + (size_t)rA * IN_DIM + (kg << 3);
    float4 xA[4], xB[4];
    #pragma unroll
    for (int s = 0; s < 4; ++s) {
        xA[s] = *reinterpret_cast<const float4*>(xp + (s << 5));
        xB[s] = *reinterpret_cast<const float4*>(xp + (s << 5) + 4);
    }

    // W^T staging: thread t covers col c = t&31, k-chunk kh = t>>5 (16 k's)
    {
        const int c = t & 31, kh = t >> 5;
        uint pk[8];
        #pragma unroll
        for (int j2 = 0; j2 < 8; ++j2) {
            const float w0 = W[(kh * 16 + 2 * j2)     * OUT_DIM + c];
            const float w1 = W[(kh * 16 + 2 * j2 + 1) * OUT_DIM + c];
            pk[j2] = (uint)rne16(w0) | ((uint)rne16(w1) << 16);
        }
        uint4* wd = reinterpret_cast<uint4*>(&WT[c][kh * 16]);
        wd[0] = make_uint4(pk[0], pk[1], pk[2], pk[3]);
        wd[1] = make_uint4(pk[4], pk[5], pk[6], pk[7]);
        if (t < OUT_DIM) { asl[t] = a_src[t]; adl[t] = a_dst[t]; }
    }
    __syncthreads();

    // B fragments: one ds_read_b128 each (cols m and m+16, k-window of s,kg)
    bf16x8 b0[4], b1[4];
    #pragma unroll
    for (int s = 0; s < 4; ++s) {
        b0[s] = *reinterpret_cast<bf16x8*>(&WT[m][(s << 5) + (kg << 3)]);
        b1[s] = *reinterpret_cast<bf16x8*>(&WT[m + 16][(s << 5) + (kg << 3)]);
    }

    f32x4 acc0 = {0.f, 0.f, 0.f, 0.f};
    f32x4 acc1 = {0.f, 0.f, 0.f, 0.f};

    #pragma unroll
    for (int s = 0; s < 4; ++s) {
        float xs[8] = {xA[s].x, xA[s].y, xA[s].z, xA[s].w,
                       xB[s].x, xB[s].y, xB[s].z, xB[s].w};
        bf16x8 ah;
        #pragma unroll
        for (int j = 0; j < 8; ++j) ah[j] = (short)rne16(xs[j]);
        acc0 = __builtin_amdgcn_mfma_f32_16x16x32_bf16(ah, b0[s], acc0, 0, 0, 0);
        acc1 = __builtin_amdgcn_mfma_f32_16x16x32_bf16(ah, b1[s], acc1, 0, 0, 0);
    }

    // attention scalars: per-row dot over 32 cols, 16-lane butterfly
    const float as0 = asl[m], as1 = asl[m + 16];
    const float ad0 = adl[m], ad1 = adl[m + 16];
    float ps[4], pd[4];
    #pragma unroll
    for (int r = 0; r < 4; ++r) {
        ps[r] = acc0[r] * as0 + acc1[r] * as1;
        pd[r] = acc0[r] * ad0 + acc1[r] * ad1;
    }
    #pragma unroll
    for (int r = 0; r < 4; ++r) {
        #pragma unroll
        for (int msk = 1; msk <= 8; msk <<= 1) {
            ps[r] += __shfl_xor(ps[r], msk, 64);
            pd[r] += __shfl_xor(pd[r], msk, 64);
        }
    }

    const int rbase = blockIdx.x * 64 + wv * 16 + (kg << 2);  // D rows 4kg+r
    if (m == 0) {
        #pragma unroll
        for (int r = 0; r < 4; ++r)
            if (rbase + r < N_NODES) ssrc[rbase + r] = ps[r];
    }
    if (m == 1) {
        #pragma unroll
        for (int r = 0; r < 4; ++r)
            if (rbase + r < N_NODES) sdst[rbase + r] = pd[r];
    }

    // z store: bf16 ushorts, layout zu16[row*32 + c]
    #pragma unroll
    for (int r = 0; r < 4; ++r) {
        const int row = rbase + r;
        if (row < N_NODES) {
            zu16[row * OUT_DIM + m]      = rne16(acc0[r]);
            zu16[row * OUT_DIM + m + 16] = rne16(acc1[r]);
        }
    }
}

// ---------------- Kernel C: fused exp + gather + normalize ----------------
// EXACT round-7 structure (measured best). 32-lane group per dst node.
// Staging: coalesced src, L2-hot ssrc gather, exp -> LDS, zero-pad. Gather:
// lane = (eh=c>>2 edge slot, ci=c&3); one unrolled block with ALL FOUR b128
// gathers issued before any FMA (max MLP — the cnt>16 branch variant
// measurably hurt by draining u0/u1 before issuing u2/u3).
__global__ __launch_bounds__(256) void agg_kernel(
    const uint* __restrict__ zu, const float* __restrict__ ssrc,
    const float* __restrict__ sdst, const int* __restrict__ src,
    const int* __restrict__ off, float* __restrict__ out)
{
    __shared__ float2 sw[8][64];
    const int t = threadIdx.x;
    const int g = t >> 5, c = t & 31;
    const int n = blockIdx.x * 8 + g;
    if (n >= N_NODES) return;

    const int lo = off[n], hi = off[n + 1];
    const float sd = sdst[n];
    const int eh = c >> 2;     // edge slot 0..7
    const int ci = c & 3;      // uint4 index within z row

    float a0 = 0.f, a1 = 0.f, a2 = 0.f, a3 = 0.f;
    float a4 = 0.f, a5 = 0.f, a6 = 0.f, a7 = 0.f;
    float den = 0.f;

    for (int base = lo; base < hi; base += 32) {
        const int cnt = min(32, hi - base);
        sw[g][cnt + c] = make_float2(0.f, __int_as_float(0));   // zero-pad
        if (c < cnt) {
            const int e = base + c;
            const int s = src[e];
            float x = ssrc[s] + sd;
            x = (x > 0.f) ? x : LEAKY * x;
            const float v = __expf(x);
            den += v;
            sw[g][c] = make_float2(v, __int_as_float(s << 4));
        }
        const float2 p0 = sw[g][eh];
        const float2 p1 = sw[g][8 + eh];
        const float2 p2 = sw[g][16 + eh];
        const float2 p3 = sw[g][24 + eh];
        const uint4 u0 = *reinterpret_cast<const uint4*>(zu + __float_as_int(p0.y) + (ci << 2));
        const uint4 u1 = *reinterpret_cast<const uint4*>(zu + __float_as_int(p1.y) + (ci << 2));
        const uint4 u2 = *reinterpret_cast<const uint4*>(zu + __float_as_int(p2.y) + (ci << 2));
        const uint4 u3 = *reinterpret_cast<const uint4*>(zu + __float_as_int(p3.y) + (ci << 2));
        #define ACC8(P, U)                                                  \
            a0 = fmaf(P.x, __uint_as_float(U.x << 16),         a0);         \
            a1 = fmaf(P.x, __uint_as_float(U.x & 0xffff0000u), a1);         \
            a2 = fmaf(P.x, __uint_as_float(U.y << 16),         a2);         \
            a3 = fmaf(P.x, __uint_as_float(U.y & 0xffff0000u), a3);         \
            a4 = fmaf(P.x, __uint_as_float(U.z << 16),         a4);         \
            a5 = fmaf(P.x, __uint_as_float(U.z & 0xffff0000u), a5);         \
            a6 = fmaf(P.x, __uint_as_float(U.w << 16),         a6);         \
            a7 = fmaf(P.x, __uint_as_float(U.w & 0xffff0000u), a7);
        ACC8(p0, u0) ACC8(p1, u1) ACC8(p2, u2) ACC8(p3, u3)
        #undef ACC8
    }

    #pragma unroll
    for (int msk = 4; msk <= 16; msk <<= 1) {
        a0 += __shfl_xor(a0, msk, 64); a1 += __shfl_xor(a1, msk, 64);
        a2 += __shfl_xor(a2, msk, 64); a3 += __shfl_xor(a3, msk, 64);
        a4 += __shfl_xor(a4, msk, 64); a5 += __shfl_xor(a5, msk, 64);
        a6 += __shfl_xor(a6, msk, 64); a7 += __shfl_xor(a7, msk, 64);
    }
    #pragma unroll
    for (int msk = 16; msk >= 1; msk >>= 1) den += __shfl_xor(den, msk, 64);

    if (eh == 0) {
        const float inv = (den > 0.f) ? (1.f / den) : 0.f;
        float4 o0, o1;
        o0.x = fmaxf(a0 * inv, 0.f); o0.y = fmaxf(a1 * inv, 0.f);
        o0.z = fmaxf(a2 * inv, 0.f); o0.w = fmaxf(a3 * inv, 0.f);
        o1.x = fmaxf(a4 * inv, 0.f); o1.y = fmaxf(a5 * inv, 0.f);
        o1.z = fmaxf(a6 * inv, 0.f); o1.w = fmaxf(a7 * inv, 0.f);
        float* op = &out[n * OUT_DIM + (ci << 3)];
        *reinterpret_cast<float4*>(op)     = o0;
        *reinterpret_cast<float4*>(op + 4) = o1;
    }
}

// ---------------- launch ----------------
extern "C" void kernel_launch(void* const* d_in, const int* in_sizes, int n_in,
                              void* d_out, int out_size, void* d_ws, size_t ws_size,
                              hipStream_t stream) {
    const float* X     = (const float*)d_in[0];
    const float* W     = (const float*)d_in[1];
    const float* a_src = (const float*)d_in[2];
    const float* a_dst = (const float*)d_in[3];
    const int*   src   = (const int*)d_in[4];
    const int*   dst   = (const int*)d_in[5];
    float* out = (float*)d_out;

    char* ws = (char*)d_ws;
    ushort* zu16 = (ushort*)ws; ws += (size_t)N_NODES * OUT_DIM * sizeof(ushort);
    float* ssrc  = (float*)ws;  ws += (size_t)N_NODES * sizeof(float);
    float* sdst  = (float*)ws;  ws += (size_t)N_NODES * sizeof(float);
    int*   off   = (int*)ws;    ws += (size_t)(N_NODES + 1) * sizeof(int);

    gemm_off_kernel<<<GEMM_NBLK + OFF_NBLK, 256, 0, stream>>>(
        X, W, a_src, a_dst, dst, zu16, ssrc, sdst, off);
    agg_kernel<<<(N_NODES + 7) / 8, 256, 0, stream>>>((const uint*)zu16, ssrc, sdst, src, off, out);
}